// Round 3
// baseline (221.998 us; speedup 1.0000x reference)
//
#include <hip/hip_runtime.h>
#include <hip/hip_bf16.h>
#include <stdint.h>

typedef __bf16 bf16;
typedef __bf16 bf16x8 __attribute__((ext_vector_type(8)));
typedef __bf16 bf16x4 __attribute__((ext_vector_type(4)));
typedef float  f32x4  __attribute__((ext_vector_type(4)));
typedef float  f32x16 __attribute__((ext_vector_type(16)));

#define S_LEN  2048
#define NH     16
#define DKV    64
#define DMODEL 1024
#define LOG2E  1.4426950408889634f

// raw barrier + counted waits: keep loads in flight across barriers (T3/T4).
#define SBAR()       __builtin_amdgcn_s_barrier()
#define SFENCE()     __builtin_amdgcn_sched_barrier(0)
#define WAIT_VM(N)   asm volatile("s_waitcnt vmcnt(" #N ")" ::: "memory")
#define WAIT_LGKM0() asm volatile("s_waitcnt lgkmcnt(0)" ::: "memory")

// ---------------------------------------------------------------------------
// async global->LDS 16B copy. LDS dest is wave-uniform base + lane*16.
// ---------------------------------------------------------------------------
__device__ __forceinline__ void async_load16(const void* g, void* l) {
  __builtin_amdgcn_global_load_lds(
      (const __attribute__((address_space(1))) uint32_t*)(uintptr_t)g,
      (__attribute__((address_space(3))) uint32_t*)(uintptr_t)l,
      16, 0, 0);
}

// ---------------------------------------------------------------------------
// Transpose-cast W [K=1024][N=1024] fp32 -> Wt bf16 [N][K]. grid (32,32,4), block (32,8)
// ---------------------------------------------------------------------------
__global__ void transpose_w(const float* __restrict__ W0, const float* __restrict__ W1,
                            const float* __restrict__ W2, const float* __restrict__ W3,
                            bf16* __restrict__ T0, bf16* __restrict__ T1,
                            bf16* __restrict__ T2, bf16* __restrict__ T3)
{
  int z = blockIdx.z;
  const float* W = (z == 0) ? W0 : (z == 1) ? W1 : (z == 2) ? W2 : W3;
  bf16* T = (z == 0) ? T0 : (z == 1) ? T1 : (z == 2) ? T2 : T3;
  __shared__ float tile[32][33];
  int n0 = blockIdx.x * 32, k0 = blockIdx.y * 32;
  int tx = threadIdx.x, ty = threadIdx.y;
  for (int i = 0; i < 32; i += 8)
    tile[ty + i][tx] = W[(size_t)(k0 + ty + i) * DMODEL + n0 + tx];
  __syncthreads();
  for (int i = 0; i < 32; i += 8)
    T[(size_t)(n0 + ty + i) * DMODEL + k0 + tx] = (bf16)tile[tx][ty + i];
}

// ---------------------------------------------------------------------------
// QKV GEMM: fused fp32->bf16 cast on A; 64x128 tile, BK=64.
// Depth-2 A register prefetch (A streams from HBM ~900cy; depth-1 lead was
// exposed). Steady-state queue entering iter kt = [A(kt)4, B(kt)4, A(kt+1)4]:
//   +B(kt+1) -> vmcnt(12) retires A(kt) -> cvt -> +A(kt+2) -> vmcnt(12)
//   retires B(kt) -> barrier. 12 loads permanently in flight; no mid-loop
//   drain. Tails: kt=14 vmcnt(8), kt=15 vmcnt(4)/vmcnt(0).
// Even/odd A-register sets are named (no runtime-indexed reg arrays, rule #20).
// grid (m=64, n=8, z=3) = 1536 blocks; LDS 40KB.
// ---------------------------------------------------------------------------
__global__ __launch_bounds__(256) void gemm_qkv(
    const float* __restrict__ Aq, const float* __restrict__ Ak, const float* __restrict__ Av,
    const bf16* __restrict__ Bq, const bf16* __restrict__ Bk, const bf16* __restrict__ Bv,
    bf16* __restrict__ Cq, bf16* __restrict__ Ck, bf16* __restrict__ Cv)
{
  __shared__ __align__(16) char smem[40960];   // As 8K + Bs0 16K + Bs1 16K
  bf16* As  = (bf16*)smem;
  bf16* Bs0 = (bf16*)(smem + 8192);
  bf16* Bs1 = (bf16*)(smem + 8192 + 16384);
  bf16* Ls  = (bf16*)smem;               // epilogue overlay [64][132] = 16.9KB

  const int z = blockIdx.z;
  const float* A = (z == 0) ? Aq : (z == 1) ? Ak : Av;
  const bf16* Bt = (z == 0) ? Bq : (z == 1) ? Bk : Bv;
  bf16* C        = (z == 0) ? Cq : (z == 1) ? Ck : Cv;

  const int m0 = blockIdx.x * 64;        // m on x: XCD-local A reuse
  const int n0 = blockIdx.y * 128;
  const int tid = threadIdx.x;
  const int lane = tid & 63;
  const int wave = tid >> 6;
  const int wm = (wave >> 1) * 32;
  const int wn = (wave & 1) * 64;
  const int row = lane & 15;
  const int quad = lane >> 4;

  f32x4 acc[2][4];
  for (int i = 0; i < 2; ++i)
    for (int j = 0; j < 4; ++j) acc[i][j] = (f32x4){0.f, 0.f, 0.f, 0.f};

  const int arc = tid & 7;
  const int arr = tid >> 3;              // 0..31; second A row adds 32
  const float* A0p = A + (size_t)(m0 + arr) * DMODEL + arc * 8;
  const float* A1p = A + (size_t)(m0 + 32 + arr) * DMODEL + arc * 8;

  // 4 async ops/thread: stage B k-tile kt into Bsel (XOR-swizzle in src addr)
  auto stageB = [&](int kt, bf16* Bsel) {
    const int kk = kt << 6;
    for (int j = 0; j < 4; ++j) {
      int base = j * 256 + wave * 64;
      int idx = base + lane;
      int r = idx >> 3;
      int cc = (idx & 7) ^ (r & 7);
      async_load16(Bt + (size_t)(n0 + r) * DMODEL + kk + cc * 8,
                   (char*)Bsel + (size_t)base * 16);
    }
  };

  // depth-2 A prefetch registers: even set (a*), odd set (b*)
  f32x4 a00, a01, a10, a11;              // A(even kt): c00=A0p lo, c01=A0p hi, c10=A1p lo, c11=A1p hi
  f32x4 b00, b01, b10, b11;              // A(odd kt)

  // prologue issue order (pinned): A(0)[4] -> B(0)[4] -> A(1)[4]
  a00 = *(const f32x4*)(A0p);
  a01 = *(const f32x4*)(A0p + 4);
  a10 = *(const f32x4*)(A1p);
  a11 = *(const f32x4*)(A1p + 4);
  SFENCE();
  stageB(0, Bs0);
  SFENCE();
  b00 = *(const f32x4*)(A0p + 64);
  b01 = *(const f32x4*)(A0p + 68);
  b10 = *(const f32x4*)(A1p + 64);
  b11 = *(const f32x4*)(A1p + 68);
  SFENCE();

  // one K-step: consumes (c00..c11)=A(kt), reloads the same set with A(kt+2).
  // Pack order matches round-1: row arr <- {c00,c01}, row arr+32 <- {c10,c11}.
  auto body = [&](int kt, f32x4& c00, f32x4& c01, f32x4& c10, f32x4& c11,
                  bf16* Bcur, bf16* Bnxt) {
    if (kt < 15) stageB(kt + 1, Bnxt);   // Bnxt free since end-barrier(kt-1)
    SFENCE();
    if (kt < 15) { WAIT_VM(12); } else { WAIT_VM(4); }   // A(kt) landed
    SFENCE();
    {                                     // cvt + swizzled LDS write of A(kt)
      bf16x8 o;
      for (int w = 0; w < 4; ++w) { o[w] = (bf16)c00[w]; o[w + 4] = (bf16)c01[w]; }
      *(bf16x8*)(As + arr * 64 + ((arc ^ (arr & 7)) << 3)) = o;
      int r2 = 32 + arr;
      for (int w = 0; w < 4; ++w) { o[w] = (bf16)c10[w]; o[w + 4] = (bf16)c11[w]; }
      *(bf16x8*)(As + r2 * 64 + ((arc ^ (r2 & 7)) << 3)) = o;
    }
    SFENCE();
    if (kt < 14) {                        // issue A(kt+2) into the freed set
      const int kn = (kt + 2) << 6;
      c00 = *(const f32x4*)(A0p + kn);
      c01 = *(const f32x4*)(A0p + kn + 4);
      c10 = *(const f32x4*)(A1p + kn);
      c11 = *(const f32x4*)(A1p + kn + 4);
    }
    SFENCE();
    if (kt < 14)      { WAIT_VM(12); }    // B(kt) landed, 12 newest in flight
    else if (kt == 14){ WAIT_VM(8); }
    else              { WAIT_VM(0); }
    WAIT_LGKM0();                         // As writes visible
    SBAR();                               // mid-barrier: tile published
    SFENCE();
    for (int ks = 0; ks < 2; ++ks) {
      bf16x8 af[2], bfr[4];
      for (int i = 0; i < 2; ++i) {
        int rr = wm + i * 16 + row;
        af[i] = *(const bf16x8*)(As + rr * 64 + (((quad + ks * 4) ^ (rr & 7)) << 3));
      }
      for (int j = 0; j < 4; ++j) {
        int rr = wn + j * 16 + row;
        bfr[j] = *(const bf16x8*)(Bcur + rr * 64 + (((quad + ks * 4) ^ (rr & 7)) << 3));
      }
      for (int i = 0; i < 2; ++i)
        for (int j = 0; j < 4; ++j)
          acc[i][j] = __builtin_amdgcn_mfma_f32_16x16x32_bf16(af[i], bfr[j], acc[i][j], 0, 0, 0);
    }
    SFENCE();
    SBAR();                               // end-barrier: readers of As/Bcur done
  };

  for (int kh = 0; kh < 8; ++kh) {
    body(2 * kh,     a00, a01, a10, a11, Bs0, Bs1);   // even kt: cur=Bs0, next=Bs1
    body(2 * kh + 1, b00, b01, b10, b11, Bs1, Bs0);   // odd  kt: cur=Bs1, next=Bs0
  }

  if (z != 2) {
    // LDS-restaged coalesced epilogue -> [B,NH,S,DKV], single pass (64 rows)
    const int bq = m0 >> 11;
    __syncthreads();                      // full drain ok here (loop finished)
    for (int i = 0; i < 2; ++i)
      for (int j = 0; j < 4; ++j)
        for (int r = 0; r < 4; ++r)
          Ls[(wm + i * 16 + quad * 4 + r) * 132 + wn + j * 16 + row] = (bf16)acc[i][j][r];
    __syncthreads();
    for (int u = 0; u < 4; ++u) {
      int cc = u * 256 + tid;             // 1024 chunks of 16B
      int rloc = cc >> 4, c8 = (cc & 15) * 8;
      int s = (m0 + rloc) & 2047;
      int gn = n0 + c8;
      int h = gn >> 6, d = gn & 63;
      bf16x8 val = *(const bf16x8*)(Ls + rloc * 132 + c8);
      *(bf16x8*)(C + (((size_t)(bq * NH + h)) * S_LEN + s) * DKV + d) = val;
    }
  } else {
    // V permuted for attn PV: [bh][tile=s/64][kb=(s%64)/4][d][sr=s%4]
    for (int i = 0; i < 2; ++i)
      for (int j = 0; j < 4; ++j) {
        int gm = m0 + wm + i * 16 + quad * 4;
        int gn = n0 + wn + j * 16 + row;
        int b = gm >> 11, s = gm & 2047;
        int h = gn >> 6,  d = gn & 63;
        int bh = b * NH + h;
        int tile = s >> 6, kb = (s & 63) >> 2;
        bf16x4 t;
        for (int r = 0; r < 4; ++r) t[r] = (bf16)acc[i][j][r];
        *(bf16x4*)(C + ((((size_t)bh * 32 + tile) * 16 + kb) * 64 + d) * 4) = t;
      }
  }
}

// ---------------------------------------------------------------------------
// Flash attention: S^T = K*Q^T via 32x32x16 MFMA; P stays in registers.
// K/V/mask double-buffered; counted vmcnt (unchanged from round 1 -- its
// staging is L2-resident and was not the bottleneck).
// grid (bh=32, q=16, zh=2); LDS 33KB.
// ---------------------------------------------------------------------------
__global__ __launch_bounds__(256, 4) void attn_kernel(
    const bf16* __restrict__ Qh, const bf16* __restrict__ Kh, const bf16* __restrict__ Vperm,
    const float* __restrict__ mask, bf16* __restrict__ Opart, float* __restrict__ Lpart)
{
  __shared__ __align__(16) bf16 Ks[2][64 * 64];    // [kv][d], chunk XOR-swizzled
  __shared__ __align__(16) bf16 Vts[2][64 * 64];   // [kb][d][4] linear (permuted)
  __shared__ __align__(16) float masks2[2][64];

  const int bh = blockIdx.x;                    // bh on x: XCD-local K/V reuse
  const int b = bh >> 4;
  const int q0 = blockIdx.y * 128;
  const int zh = blockIdx.z;                    // kv half
  const int tid = threadIdx.x;
  const int lane = tid & 63;
  const int wave = tid >> 6;
  const int ln = lane & 31;
  const int hi = lane >> 5;
  const float SC2 = 0.125f * LOG2E;

  // hoisted Q B-frags: B[k=d][n=q] = Q[q][d], d = c*16 + hi*8 + u
  const int qg = q0 + wave * 32 + ln;
  bf16x8 qf[4];
  {
    const bf16* qrow = Qh + ((size_t)bh * S_LEN + qg) * DKV;
    for (int c = 0; c < 4; ++c)
      qf[c] = *(const bf16x8*)(qrow + c * 16 + hi * 8);
  }

  auto stage = [&](int it, int buf) {
    const int kv0 = zh * 1024 + it * 64;
    float mval = 0.f;
    if (tid < 64) mval = mask[b * S_LEN + kv0 + tid];   // issued first
    const bf16* vtile = Vperm + ((size_t)bh * 32 + (kv0 >> 6)) * 4096;
    for (int j = 0; j < 2; ++j) {
      int base = j * 256 + wave * 64;
      int idx = base + lane;
      int r = idx >> 3;
      int cc = (idx & 7) ^ (r & 7);
      async_load16(Kh + ((size_t)bh * S_LEN + kv0 + r) * DKV + cc * 8,
                   (char*)Ks[buf] + (size_t)base * 16);
      async_load16(vtile + (size_t)idx * 8,
                   (char*)Vts[buf] + (size_t)base * 16);
    }
    if (tid < 64) masks2[buf][tid] = mval * LOG2E;
  };

  f32x16 O[2];
  for (int nb = 0; nb < 2; ++nb)
    for (int i = 0; i < 16; ++i) O[nb][i] = 0.f;
  float lsum = 0.f;

  stage(0, 0);                                  // prologue

  for (int it = 0; it < 16; ++it) {
    const int cur = it & 1;
    if (it < 15) stage(it + 1, cur ^ 1);        // prev readers done (end-bar it-1)
    SFENCE();
    if (it < 15) { WAIT_VM(4); }                // KV(it) landed; KV(it+1) in flight
    else         { WAIT_VM(0); }
    WAIT_LGKM0();                               // masks2 write visible
    SBAR();
    SFENCE();

    // S^T = K * Q^T  (A = K[kv][d], m=kv: 2 m-blocks; B = qf; 4 k-chunks)
    f32x16 Sm[2];
    for (int i = 0; i < 16; ++i) { Sm[0][i] = 0.f; Sm[1][i] = 0.f; }
    for (int c = 0; c < 4; ++c) {
      bf16x8 k0 = *(const bf16x8*)(Ks[cur] + ln * 64        + (((2 * c + hi) ^ (ln & 7)) << 3));
      bf16x8 k1 = *(const bf16x8*)(Ks[cur] + (32 + ln) * 64 + (((2 * c + hi) ^ (ln & 7)) << 3));
      Sm[0] = __builtin_amdgcn_mfma_f32_32x32x16_bf16(k0, qf[c], Sm[0], 0, 0, 0);
      Sm[1] = __builtin_amdgcn_mfma_f32_32x32x16_bf16(k1, qf[c], Sm[1], 0, 0, 0);
    }

    // P = exp2(S*SC2 + mask*LOG2E) in registers -> PV
    for (int cg = 0; cg < 4; ++cg) {
      int mb = cg >> 1, g = cg & 1;
      int koff = 32 * mb + 16 * g + 4 * hi;
      f32x4 mklo = *(const f32x4*)(&masks2[cur][koff]);
      f32x4 mkhi = *(const f32x4*)(&masks2[cur][koff + 8]);
      bf16x8 ap;
      float ls0 = 0.f;
      for (int u = 0; u < 4; ++u) {
        float p = __builtin_amdgcn_exp2f(Sm[mb][g * 8 + u] * SC2 + mklo[u]);
        ls0 += p; ap[u] = (bf16)p;
      }
      for (int u = 0; u < 4; ++u) {
        float p = __builtin_amdgcn_exp2f(Sm[mb][g * 8 + 4 + u] * SC2 + mkhi[u]);
        ls0 += p; ap[4 + u] = (bf16)p;
      }
      lsum += ls0;
      int kb0 = hi + 4 * g + 8 * mb;
      for (int nb = 0; nb < 2; ++nb) {
        int d = nb * 32 + ln;
        bf16x4 lo = *(const bf16x4*)(Vts[cur] + ((size_t)kb0 * 64 + d) * 4);
        bf16x4 hv = *(const bf16x4*)(Vts[cur] + ((size_t)(kb0 + 2) * 64 + d) * 4);
        bf16x8 bv;
        for (int u = 0; u < 4; ++u) { bv[u] = lo[u]; bv[u + 4] = hv[u]; }
        O[nb] = __builtin_amdgcn_mfma_f32_32x32x16_bf16(ap, bv, O[nb], 0, 0, 0);
      }
    }
    SFENCE();
    SBAR();                                     // end-barrier: tile readers done
  }

  // partial row sums
  float lt = lsum + __shfl_xor(lsum, 32, 64);
  if (lane < 32)
    Lpart[((size_t)zh * 32 + bh) * S_LEN + q0 + wave * 32 + ln] = lt;

  // partial O (un-normalized, bf16): Opart[zh][bh][q][d]
  bf16* ob = Opart + (((size_t)zh * 32 + bh) * S_LEN) * DKV;
  for (int g = 0; g < 4; ++g)
    for (int nb = 0; nb < 2; ++nb)
      for (int j = 0; j < 4; ++j) {
        int qrow = q0 + wave * 32 + j + 8 * g + 4 * hi;
        ob[(size_t)qrow * DKV + nb * 32 + ln] = (bf16)O[nb][g * 4 + j];
      }
}

// ---------------------------------------------------------------------------
// Out-GEMM: fused combine+normalize on A (bf16 partials); 32x128 tile, BK=64.
// Depth-2 h (Opart) register prefetch, same mechanism as gemm_qkv:
// steady queue entering iter kt = [h(kt)2, B(kt)4, h(kt+1)2];
//   +B(kt+1) -> vmcnt(10) retires h(kt) -> cvt -> +h(kt+2) -> vmcnt(8)
//   retires B(kt). Tails: kt=14 vmcnt(6), kt=15 vmcnt(4)/vmcnt(0).
// grid (m=128, n=8) = 1024 blocks; LDS 38KB.
// ---------------------------------------------------------------------------
__global__ __launch_bounds__(256) void gemm_out(
    const bf16* __restrict__ Opart, const float* __restrict__ Lpart,
    const bf16* __restrict__ Wot, float* __restrict__ Cout)
{
  __shared__ __align__(16) bf16 As[32 * 64];       // 4KB swizzled
  __shared__ __align__(16) bf16 Bs[2][128 * 64];   // 32KB swizzled, dbuf
  __shared__ float rinv[NH * 32];                  // 2KB

  const int m0 = blockIdx.x * 32;        // m on x: XCD-local Opart reuse
  const int n0 = blockIdx.y * 128;
  const int tid = threadIdx.x;
  const int lane = tid & 63;
  const int wave = tid >> 6;
  const int wm = (wave >> 1) * 16;
  const int wn = (wave & 1) * 64;
  const int row = lane & 15;
  const int quad = lane >> 4;
  const int b = m0 >> 11;
  const int s0 = m0 & 2047;

  // per-block row-sum reciprocals (scalar loads retire before prologue issues)
  for (int u = 0; u < 2; ++u) {
    int idx = u * 256 + tid;
    int h = idx >> 5, r = idx & 31;
    float l = Lpart[((size_t)(b * NH + h)) * S_LEN + s0 + r]
            + Lpart[((size_t)(32 + b * NH + h)) * S_LEN + s0 + r];
    rinv[idx] = 1.0f / l;
  }
  SFENCE();

  f32x4 acc[4];
  for (int j = 0; j < 4; ++j) acc[j] = (f32x4){0.f, 0.f, 0.f, 0.f};

  const int arc = tid & 7;               // chunk col
  const int arr = tid >> 3;              // row 0..31
  const bf16* O0p = Opart + ((size_t)(b * NH) * S_LEN + s0 + arr) * DKV + arc * 8;
  const bf16* O1p = Opart + ((size_t)(32 + b * NH) * S_LEN + s0 + arr) * DKV + arc * 8;
  const size_t HSTEP = (size_t)S_LEN * DKV;

  auto stageB = [&](int kt, int buf) {
    for (int j = 0; j < 4; ++j) {
      int base = j * 256 + wave * 64;
      int idx = base + lane;
      int r = idx >> 3;
      int cc = (idx & 7) ^ (r & 7);
      async_load16(Wot + (size_t)(n0 + r) * DMODEL + kt * 64 + cc * 8,
                   (char*)Bs[buf] + (size_t)base * 16);
    }
  };

  // depth-2 h prefetch: even set (ha*), odd set (hb*)
  bf16x8 ha0, ha1, hb0, hb1;
  // prologue issue order (pinned): h(0)[2] -> B(0)[4] -> h(1)[2]
  ha0 = *(const bf16x8*)(O0p);
  ha1 = *(const bf16x8*)(O1p);
  SFENCE();
  stageB(0, 0);
  SFENCE();
  hb0 = *(const bf16x8*)(O0p + HSTEP);
  hb1 = *(const bf16x8*)(O1p + HSTEP);
  SFENCE();
  WAIT_LGKM0();                          // rinv ds_writes visible
  SBAR();                                // publish rinv (no vmcnt drain)

  auto body = [&](int kt, bf16x8& c0, bf16x8& c1) {
    const int cur = kt & 1;
    if (kt < 15) stageB(kt + 1, cur ^ 1);
    SFENCE();
    if (kt < 15) { WAIT_VM(10); } else { WAIT_VM(4); }   // h(kt) landed
    SFENCE();
    {
      float rv = rinv[kt * 32 + arr];
      bf16x8 o;
      for (int w = 0; w < 8; ++w)
        o[w] = (bf16)(((float)c0[w] + (float)c1[w]) * rv);
      *(bf16x8*)(As + arr * 64 + ((arc ^ (arr & 7)) << 3)) = o;
    }
    SFENCE();
    if (kt < 14) {                       // issue h(kt+2) into freed set
      c0 = *(const bf16x8*)(O0p + (size_t)(kt + 2) * HSTEP);
      c1 = *(const bf16x8*)(O1p + (size_t)(kt + 2) * HSTEP);
    }
    SFENCE();
    if (kt < 14)      { WAIT_VM(8); }    // B(kt) landed
    else if (kt == 14){ WAIT_VM(6); }
    else              { WAIT_VM(0); }
    WAIT_LGKM0();
    SBAR();
    SFENCE();
    for (int ks = 0; ks < 2; ++ks) {
      bf16x8 af, bfr[4];
      {
        int rr = wm + row;
        af = *(const bf16x8*)(As + rr * 64 + (((quad + ks * 4) ^ (rr & 7)) << 3));
      }
      for (int j = 0; j < 4; ++j) {
        int rr = wn + j * 16 + row;
        bfr[j] = *(const bf16x8*)(Bs[cur] + rr * 64 + (((quad + ks * 4) ^ (rr & 7)) << 3));
      }
      for (int j = 0; j < 4; ++j)
        acc[j] = __builtin_amdgcn_mfma_f32_16x16x32_bf16(af, bfr[j], acc[j], 0, 0, 0);
    }
    SFENCE();
    SBAR();
  };

  for (int kh = 0; kh < 8; ++kh) {
    body(2 * kh,     ha0, ha1);
    body(2 * kh + 1, hb0, hb1);
  }

  for (int j = 0; j < 4; ++j)
    for (int r = 0; r < 4; ++r) {
      int gm = m0 + wm + quad * 4 + r;
      int gn = n0 + wn + j * 16 + row;
      Cout[(size_t)gm * DMODEL + gn] = acc[j][r];
    }
}

// ---------------------------------------------------------------------------
extern "C" void kernel_launch(void* const* d_in, const int* in_sizes, int n_in,
                              void* d_out, int out_size, void* d_ws, size_t ws_size,
                              hipStream_t stream)
{
  const float* query = (const float*)d_in[0];
  const float* key_  = (const float*)d_in[1];
  const float* value = (const float*)d_in[2];
  const float* mask  = (const float*)d_in[3];
  const float* Wq = (const float*)d_in[4];
  const float* Wk = (const float*)d_in[5];
  const float* Wv = (const float*)d_in[6];
  const float* Wo = (const float*)d_in[7];

  char* ws = (char*)d_ws;
  const size_t MB = (size_t)1 << 20;
  bf16* qh    = (bf16*)(ws + 0 * MB);    // 8MB [B,NH,S,DKV]
  bf16* kh    = (bf16*)(ws + 8 * MB);    // 8MB [B,NH,S,DKV]
  bf16* vperm = (bf16*)(ws + 16 * MB);   // 8MB PV-permuted V
  bf16* wot   = (bf16*)(ws + 24 * MB);   // 2MB (live until out-GEMM)
  bf16* Opart = (bf16*)(ws + 26 * MB);   // 16MB bf16 partials (26..42)
  bf16* wqt   = (bf16*)(ws + 26 * MB);   // 2MB each, dead after QKV GEMM
  bf16* wkt   = (bf16*)(ws + 28 * MB);   //   (overlaid by Opart afterwards)
  bf16* wvt   = (bf16*)(ws + 30 * MB);
  float* Lpart = (float*)(ws + 58 * MB); // 512KB row-sum partials

  transpose_w<<<dim3(32, 32, 4), dim3(32, 8), 0, stream>>>(Wq, Wk, Wv, Wo, wqt, wkt, wvt, wot);
  gemm_qkv<<<dim3(64, 8, 3), 256, 0, stream>>>(query, key_, value, wqt, wkt, wvt,
                                               qh, kh, vperm);
  attn_kernel<<<dim3(32, 16, 2), 256, 0, stream>>>(qh, kh, vperm, mask, Opart, Lpart);
  gemm_out<<<dim3(128, 8), 256, 0, stream>>>(Opart, Lpart, wot, (float*)d_out);
}

// Round 4
// 208.720 us; speedup vs baseline: 1.0636x; 1.0636x over previous
//
#include <hip/hip_runtime.h>
#include <hip/hip_bf16.h>
#include <stdint.h>

typedef __bf16 bf16;
typedef __bf16 bf16x8 __attribute__((ext_vector_type(8)));
typedef __bf16 bf16x4 __attribute__((ext_vector_type(4)));
typedef float  f32x4  __attribute__((ext_vector_type(4)));
typedef float  f32x16 __attribute__((ext_vector_type(16)));

#define S_LEN  2048
#define NH     16
#define DKV    64
#define DMODEL 1024
#define LOG2E  1.4426950408889634f

// raw barrier + counted waits: keep loads in flight across barriers (T3/T4).
#define SBAR()       __builtin_amdgcn_s_barrier()
#define SFENCE()     __builtin_amdgcn_sched_barrier(0)
#define WAIT_VM(N)   asm volatile("s_waitcnt vmcnt(" #N ")" ::: "memory")
#define WAIT_LGKM0() asm volatile("s_waitcnt lgkmcnt(0)" ::: "memory")

// ---------------------------------------------------------------------------
// async global->LDS 16B copy. LDS dest is wave-uniform base + lane*16.
// ---------------------------------------------------------------------------
__device__ __forceinline__ void async_load16(const void* g, void* l) {
  __builtin_amdgcn_global_load_lds(
      (const __attribute__((address_space(1))) uint32_t*)(uintptr_t)g,
      (__attribute__((address_space(3))) uint32_t*)(uintptr_t)l,
      16, 0, 0);
}

// ---------------------------------------------------------------------------
// Transpose-cast W [K=1024][N=1024] fp32 -> Wt bf16 [N][K]. grid (32,32,4), block (32,8)
// ---------------------------------------------------------------------------
__global__ void transpose_w(const float* __restrict__ W0, const float* __restrict__ W1,
                            const float* __restrict__ W2, const float* __restrict__ W3,
                            bf16* __restrict__ T0, bf16* __restrict__ T1,
                            bf16* __restrict__ T2, bf16* __restrict__ T3)
{
  int z = blockIdx.z;
  const float* W = (z == 0) ? W0 : (z == 1) ? W1 : (z == 2) ? W2 : W3;
  bf16* T = (z == 0) ? T0 : (z == 1) ? T1 : (z == 2) ? T2 : T3;
  __shared__ float tile[32][33];
  int n0 = blockIdx.x * 32, k0 = blockIdx.y * 32;
  int tx = threadIdx.x, ty = threadIdx.y;
  for (int i = 0; i < 32; i += 8)
    tile[ty + i][tx] = W[(size_t)(k0 + ty + i) * DMODEL + n0 + tx];
  __syncthreads();
  for (int i = 0; i < 32; i += 8)
    T[(size_t)(n0 + ty + i) * DMODEL + k0 + tx] = (bf16)tile[tx][ty + i];
}

// ---------------------------------------------------------------------------
// QKV GEMM: fused fp32->bf16 cast on A; 128x128 tile, BK=64 (was 64x128).
// Rationale: 64-tile wave did 16 MFMA per 12 ds_read_b128 (LDS-issue-bound,
// matches guide's 64^2=343 TF vs 128^2=874 TF ladder). 128^2 wave = 64x64
// output, 32 MFMA per 16 b128. Round-1 depth-1 schedule kept verbatim:
//   stageB(kt+1) -> cvt A(kt) [compiler wait vmcnt(4) = 1-iter-lead loads]
//   -> prefetch A(kt+1) regs -> vmcnt(12) (no-op guard) -> lgkm -> SBAR
//   -> MFMA -> SBAR.  B(kt+1) DMAs stay in flight across both barriers.
// grid (m=32, n=8, z=3) = 768 blocks = 3/CU exact residency; LDS 48KB.
// ---------------------------------------------------------------------------
__global__ __launch_bounds__(256) void gemm_qkv(
    const float* __restrict__ Aq, const float* __restrict__ Ak, const float* __restrict__ Av,
    const bf16* __restrict__ Bq, const bf16* __restrict__ Bk, const bf16* __restrict__ Bv,
    bf16* __restrict__ Cq, bf16* __restrict__ Ck, bf16* __restrict__ Cv)
{
  __shared__ __align__(16) char smem[49152];   // As 16K [128][64] + Bs0/Bs1 16K each
  bf16* As  = (bf16*)smem;
  bf16* Bs0 = (bf16*)(smem + 16384);
  bf16* Bs1 = (bf16*)(smem + 32768);
  bf16* Ls  = (bf16*)smem;               // epilogue overlay [128][132] = 33.8KB

  const int z = blockIdx.z;
  const float* A = (z == 0) ? Aq : (z == 1) ? Ak : Av;
  const bf16* Bt = (z == 0) ? Bq : (z == 1) ? Bk : Bv;
  bf16* C        = (z == 0) ? Cq : (z == 1) ? Ck : Cv;

  const int m0 = blockIdx.x * 128;       // m on x: XCD-local A reuse
  const int n0 = blockIdx.y * 128;
  const int tid = threadIdx.x;
  const int lane = tid & 63;
  const int wave = tid >> 6;
  const int wm = (wave >> 1) * 64;       // wave output: 64x64
  const int wn = (wave & 1) * 64;
  const int row = lane & 15;
  const int quad = lane >> 4;

  f32x4 acc[4][4];
  for (int i = 0; i < 4; ++i)
    for (int j = 0; j < 4; ++j) acc[i][j] = (f32x4){0.f, 0.f, 0.f, 0.f};

  // A staging: 128 rows as 4 groups of 32; thread handles row g*32+arr, chunk arc
  const int arc = tid & 7;
  const int arr = tid >> 3;              // 0..31
  const float* Ap0 = A + (size_t)(m0 +  0 + arr) * DMODEL + arc * 8;
  const float* Ap1 = A + (size_t)(m0 + 32 + arr) * DMODEL + arc * 8;
  const float* Ap2 = A + (size_t)(m0 + 64 + arr) * DMODEL + arc * 8;
  const float* Ap3 = A + (size_t)(m0 + 96 + arr) * DMODEL + arc * 8;

  // 4 async ops/thread: stage B k-tile kt into Bsel (XOR-swizzle in src addr)
  auto stageB = [&](int kt, bf16* Bsel) {
    const int kk = kt << 6;
    for (int j = 0; j < 4; ++j) {
      int base = j * 256 + wave * 64;
      int idx = base + lane;
      int r = idx >> 3;
      int cc = (idx & 7) ^ (r & 7);
      async_load16(Bt + (size_t)(n0 + r) * DMODEL + kk + cc * 8,
                   (char*)Bsel + (size_t)base * 16);
    }
  };

  // depth-1 A prefetch regs: av[g][0]=cols 0..3, av[g][1]=cols 4..7 (g unrolled)
  f32x4 av[4][2];
  av[0][0] = *(const f32x4*)(Ap0); av[0][1] = *(const f32x4*)(Ap0 + 4);
  av[1][0] = *(const f32x4*)(Ap1); av[1][1] = *(const f32x4*)(Ap1 + 4);
  av[2][0] = *(const f32x4*)(Ap2); av[2][1] = *(const f32x4*)(Ap2 + 4);
  av[3][0] = *(const f32x4*)(Ap3); av[3][1] = *(const f32x4*)(Ap3 + 4);
  SFENCE();
  stageB(0, Bs0);
  SFENCE();

  for (int kt = 0; kt < 16; ++kt) {
    bf16* Bcur = (kt & 1) ? Bs1 : Bs0;
    bf16* Bnxt = (kt & 1) ? Bs0 : Bs1;
    if (kt < 15) stageB(kt + 1, Bnxt);   // Bnxt free since end-barrier(kt-1)
#pragma unroll
    for (int g = 0; g < 4; ++g) {        // cvt + swizzled LDS write of A(kt)
      bf16x8 o;
      for (int w = 0; w < 4; ++w) { o[w] = (bf16)av[g][0][w]; o[w + 4] = (bf16)av[g][1][w]; }
      int r = g * 32 + arr;              // (r&7)==(arr&7): g*32 ≡ 0 mod 8
      *(bf16x8*)(As + r * 64 + ((arc ^ (arr & 7)) << 3)) = o;
    }
    if (kt < 15) {                       // prefetch A(kt+1): lands during MFMA
      const int kn = (kt + 1) << 6;
      av[0][0] = *(const f32x4*)(Ap0 + kn); av[0][1] = *(const f32x4*)(Ap0 + kn + 4);
      av[1][0] = *(const f32x4*)(Ap1 + kn); av[1][1] = *(const f32x4*)(Ap1 + kn + 4);
      av[2][0] = *(const f32x4*)(Ap2 + kn); av[2][1] = *(const f32x4*)(Ap2 + kn + 4);
      av[3][0] = *(const f32x4*)(Ap3 + kn); av[3][1] = *(const f32x4*)(Ap3 + kn + 4);
    }
    SFENCE();
    if (kt < 15) { WAIT_VM(12); }        // guard: B(kt+1)4 + av(kt+1)8 in flight
    else         { WAIT_VM(0); }
    WAIT_LGKM0();                        // As writes visible
    SBAR();                              // mid-barrier: tile published
    SFENCE();
    for (int ks = 0; ks < 2; ++ks) {
      bf16x8 af[4], bfr[4];
      for (int i = 0; i < 4; ++i) {
        int rr = wm + i * 16 + row;
        af[i] = *(const bf16x8*)(As + rr * 64 + (((quad + ks * 4) ^ (rr & 7)) << 3));
      }
      for (int j = 0; j < 4; ++j) {
        int rr = wn + j * 16 + row;
        bfr[j] = *(const bf16x8*)(Bcur + rr * 64 + (((quad + ks * 4) ^ (rr & 7)) << 3));
      }
      for (int i = 0; i < 4; ++i)
        for (int j = 0; j < 4; ++j)
          acc[i][j] = __builtin_amdgcn_mfma_f32_16x16x32_bf16(af[i], bfr[j], acc[i][j], 0, 0, 0);
    }
    SFENCE();
    SBAR();                              // end-barrier: readers of As/Bcur done
  }

  if (z != 2) {
    // LDS-restaged coalesced epilogue -> [B,NH,S,DKV], single pass (128 rows)
    const int bq = m0 >> 11;             // 128-row tile never crosses b boundary
    __syncthreads();                     // full drain ok (loop finished)
    for (int i = 0; i < 4; ++i)
      for (int j = 0; j < 4; ++j)
        for (int r = 0; r < 4; ++r)
          Ls[(wm + i * 16 + quad * 4 + r) * 132 + wn + j * 16 + row] = (bf16)acc[i][j][r];
    __syncthreads();
    for (int u = 0; u < 8; ++u) {
      int cc = u * 256 + tid;            // 2048 chunks of 16B
      int rloc = cc >> 4, c8 = (cc & 15) * 8;
      int s = (m0 + rloc) & 2047;
      int gn = n0 + c8;
      int h = gn >> 6, d = gn & 63;
      bf16x8 val = *(const bf16x8*)(Ls + rloc * 132 + c8);
      *(bf16x8*)(C + (((size_t)(bq * NH + h)) * S_LEN + s) * DKV + d) = val;
    }
  } else {
    // V permuted for attn PV: [bh][tile=s/64][kb=(s%64)/4][d][sr=s%4]
    for (int i = 0; i < 4; ++i)
      for (int j = 0; j < 4; ++j) {
        int gm = m0 + wm + i * 16 + quad * 4;    // s base (r=0..3 consecutive)
        int gn = n0 + wn + j * 16 + row;
        int b = gm >> 11, s = gm & 2047;
        int h = gn >> 6,  d = gn & 63;
        int bh = b * NH + h;
        int tile = s >> 6, kb = (s & 63) >> 2;
        bf16x4 t;
        for (int r = 0; r < 4; ++r) t[r] = (bf16)acc[i][j][r];
        *(bf16x4*)(C + ((((size_t)bh * 32 + tile) * 16 + kb) * 64 + d) * 4) = t;
      }
  }
}

// ---------------------------------------------------------------------------
// Flash attention: S^T = K*Q^T via 32x32x16 MFMA; P stays in registers.
// K/V/mask double-buffered; counted vmcnt. (round-1 version, unchanged)
// grid (bh=32, q=16, zh=2); LDS 33KB.
// ---------------------------------------------------------------------------
__global__ __launch_bounds__(256, 4) void attn_kernel(
    const bf16* __restrict__ Qh, const bf16* __restrict__ Kh, const bf16* __restrict__ Vperm,
    const float* __restrict__ mask, bf16* __restrict__ Opart, float* __restrict__ Lpart)
{
  __shared__ __align__(16) bf16 Ks[2][64 * 64];    // [kv][d], chunk XOR-swizzled
  __shared__ __align__(16) bf16 Vts[2][64 * 64];   // [kb][d][4] linear (permuted)
  __shared__ __align__(16) float masks2[2][64];

  const int bh = blockIdx.x;                    // bh on x: XCD-local K/V reuse
  const int b = bh >> 4;
  const int q0 = blockIdx.y * 128;
  const int zh = blockIdx.z;                    // kv half
  const int tid = threadIdx.x;
  const int lane = tid & 63;
  const int wave = tid >> 6;
  const int ln = lane & 31;
  const int hi = lane >> 5;
  const float SC2 = 0.125f * LOG2E;

  // hoisted Q B-frags: B[k=d][n=q] = Q[q][d], d = c*16 + hi*8 + u
  const int qg = q0 + wave * 32 + ln;
  bf16x8 qf[4];
  {
    const bf16* qrow = Qh + ((size_t)bh * S_LEN + qg) * DKV;
    for (int c = 0; c < 4; ++c)
      qf[c] = *(const bf16x8*)(qrow + c * 16 + hi * 8);
  }

  auto stage = [&](int it, int buf) {
    const int kv0 = zh * 1024 + it * 64;
    float mval = 0.f;
    if (tid < 64) mval = mask[b * S_LEN + kv0 + tid];   // issued first
    const bf16* vtile = Vperm + ((size_t)bh * 32 + (kv0 >> 6)) * 4096;
    for (int j = 0; j < 2; ++j) {
      int base = j * 256 + wave * 64;
      int idx = base + lane;
      int r = idx >> 3;
      int cc = (idx & 7) ^ (r & 7);
      async_load16(Kh + ((size_t)bh * S_LEN + kv0 + r) * DKV + cc * 8,
                   (char*)Ks[buf] + (size_t)base * 16);
      async_load16(vtile + (size_t)idx * 8,
                   (char*)Vts[buf] + (size_t)base * 16);
    }
    if (tid < 64) masks2[buf][tid] = mval * LOG2E;
  };

  f32x16 O[2];
  for (int nb = 0; nb < 2; ++nb)
    for (int i = 0; i < 16; ++i) O[nb][i] = 0.f;
  float lsum = 0.f;

  stage(0, 0);                                  // prologue

  for (int it = 0; it < 16; ++it) {
    const int cur = it & 1;
    if (it < 15) stage(it + 1, cur ^ 1);        // prev readers done (end-bar it-1)
    SFENCE();
    if (it < 15) { WAIT_VM(4); }                // KV(it) landed; KV(it+1) in flight
    else         { WAIT_VM(0); }
    WAIT_LGKM0();                               // masks2 write visible
    SBAR();
    SFENCE();

    // S^T = K * Q^T  (A = K[kv][d], m=kv: 2 m-blocks; B = qf; 4 k-chunks)
    f32x16 Sm[2];
    for (int i = 0; i < 16; ++i) { Sm[0][i] = 0.f; Sm[1][i] = 0.f; }
    for (int c = 0; c < 4; ++c) {
      bf16x8 k0 = *(const bf16x8*)(Ks[cur] + ln * 64        + (((2 * c + hi) ^ (ln & 7)) << 3));
      bf16x8 k1 = *(const bf16x8*)(Ks[cur] + (32 + ln) * 64 + (((2 * c + hi) ^ (ln & 7)) << 3));
      Sm[0] = __builtin_amdgcn_mfma_f32_32x32x16_bf16(k0, qf[c], Sm[0], 0, 0, 0);
      Sm[1] = __builtin_amdgcn_mfma_f32_32x32x16_bf16(k1, qf[c], Sm[1], 0, 0, 0);
    }

    // P = exp2(S*SC2 + mask*LOG2E) in registers -> PV
    for (int cg = 0; cg < 4; ++cg) {
      int mb = cg >> 1, g = cg & 1;
      int koff = 32 * mb + 16 * g + 4 * hi;
      f32x4 mklo = *(const f32x4*)(&masks2[cur][koff]);
      f32x4 mkhi = *(const f32x4*)(&masks2[cur][koff + 8]);
      bf16x8 ap;
      float ls0 = 0.f;
      for (int u = 0; u < 4; ++u) {
        float p = __builtin_amdgcn_exp2f(Sm[mb][g * 8 + u] * SC2 + mklo[u]);
        ls0 += p; ap[u] = (bf16)p;
      }
      for (int u = 0; u < 4; ++u) {
        float p = __builtin_amdgcn_exp2f(Sm[mb][g * 8 + 4 + u] * SC2 + mkhi[u]);
        ls0 += p; ap[4 + u] = (bf16)p;
      }
      lsum += ls0;
      int kb0 = hi + 4 * g + 8 * mb;
      for (int nb = 0; nb < 2; ++nb) {
        int d = nb * 32 + ln;
        bf16x4 lo = *(const bf16x4*)(Vts[cur] + ((size_t)kb0 * 64 + d) * 4);
        bf16x4 hv = *(const bf16x4*)(Vts[cur] + ((size_t)(kb0 + 2) * 64 + d) * 4);
        bf16x8 bv;
        for (int u = 0; u < 4; ++u) { bv[u] = lo[u]; bv[u + 4] = hv[u]; }
        O[nb] = __builtin_amdgcn_mfma_f32_32x32x16_bf16(ap, bv, O[nb], 0, 0, 0);
      }
    }
    SFENCE();
    SBAR();                                     // end-barrier: tile readers done
  }

  // partial row sums
  float lt = lsum + __shfl_xor(lsum, 32, 64);
  if (lane < 32)
    Lpart[((size_t)zh * 32 + bh) * S_LEN + q0 + wave * 32 + ln] = lt;

  // partial O (un-normalized, bf16): Opart[zh][bh][q][d]
  bf16* ob = Opart + (((size_t)zh * 32 + bh) * S_LEN) * DKV;
  for (int g = 0; g < 4; ++g)
    for (int nb = 0; nb < 2; ++nb)
      for (int j = 0; j < 4; ++j) {
        int qrow = q0 + wave * 32 + j + 8 * g + 4 * hi;
        ob[(size_t)qrow * DKV + nb * 32 + ln] = (bf16)O[nb][g * 4 + j];
      }
}

// ---------------------------------------------------------------------------
// Out-GEMM: fused combine+normalize on A (bf16 partials); 32x128 tile, BK=64.
// (round-1 version, unchanged: depth-1 h prefetch + B dbuf + counted vmcnt)
// grid (m=128, n=8) = 1024 blocks; LDS 38KB.
// ---------------------------------------------------------------------------
__global__ __launch_bounds__(256) void gemm_out(
    const bf16* __restrict__ Opart, const float* __restrict__ Lpart,
    const bf16* __restrict__ Wot, float* __restrict__ Cout)
{
  __shared__ __align__(16) bf16 As[32 * 64];       // 4KB swizzled
  __shared__ __align__(16) bf16 Bs[2][128 * 64];   // 32KB swizzled, dbuf
  __shared__ float rinv[NH * 32];                  // 2KB

  const int m0 = blockIdx.x * 32;        // m on x: XCD-local Opart reuse
  const int n0 = blockIdx.y * 128;
  const int tid = threadIdx.x;
  const int lane = tid & 63;
  const int wave = tid >> 6;
  const int wm = (wave >> 1) * 16;
  const int wn = (wave & 1) * 64;
  const int row = lane & 15;
  const int quad = lane >> 4;
  const int b = m0 >> 11;
  const int s0 = m0 & 2047;

  // per-block row-sum reciprocals for all heads x 32 rows
  for (int u = 0; u < 2; ++u) {
    int idx = u * 256 + tid;
    int h = idx >> 5, r = idx & 31;
    float l = Lpart[((size_t)(b * NH + h)) * S_LEN + s0 + r]
            + Lpart[((size_t)(32 + b * NH + h)) * S_LEN + s0 + r];
    rinv[idx] = 1.0f / l;
  }

  f32x4 acc[4];
  for (int j = 0; j < 4; ++j) acc[j] = (f32x4){0.f, 0.f, 0.f, 0.f};

  const int arc = tid & 7;               // chunk col
  const int arr = tid >> 3;              // row 0..31
  const bf16* O0p = Opart + ((size_t)(b * NH) * S_LEN + s0 + arr) * DKV + arc * 8;
  const bf16* O1p = Opart + ((size_t)(32 + b * NH) * S_LEN + s0 + arr) * DKV + arc * 8;
  const size_t HSTEP = (size_t)S_LEN * DKV;

  auto stageB = [&](int kt, int buf) {
    for (int j = 0; j < 4; ++j) {
      int base = j * 256 + wave * 64;
      int idx = base + lane;
      int r = idx >> 3;
      int cc = (idx & 7) ^ (r & 7);
      async_load16(Wot + (size_t)(n0 + r) * DMODEL + kt * 64 + cc * 8,
                   (char*)Bs[buf] + (size_t)base * 16);
    }
  };

  stageB(0, 0);                          // prologue: B(0) in flight
  bf16x8 h0 = *(const bf16x8*)(O0p);     // preload Opart(0)
  bf16x8 h1 = *(const bf16x8*)(O1p);
  WAIT_LGKM0();                          // rinv ds_writes visible
  SBAR();                                // publish rinv (no vmcnt drain)

  for (int kt = 0; kt < 16; ++kt) {      // kt == head index (BK=64 == DKV)
    const int cur = kt & 1;
    if (kt < 15) stageB(kt + 1, cur ^ 1);
    {
      float rv = rinv[kt * 32 + arr];
      bf16x8 o;
      for (int w = 0; w < 8; ++w)
        o[w] = (bf16)(((float)h0[w] + (float)h1[w]) * rv);
      *(bf16x8*)(As + arr * 64 + ((arc ^ (arr & 7)) << 3)) = o;
    }
    if (kt < 15) {                       // prefetch Opart(kt+1) during MFMA
      h0 = *(const bf16x8*)(O0p + (size_t)(kt + 1) * HSTEP);
      h1 = *(const bf16x8*)(O1p + (size_t)(kt + 1) * HSTEP);
    }
    SFENCE();
    if (kt < 15) { WAIT_VM(6); }         // B(kt) landed; B(kt+1)+h(kt+1) in flight
    else         { WAIT_VM(0); }
    WAIT_LGKM0();
    SBAR();
    SFENCE();
    for (int ks = 0; ks < 2; ++ks) {
      bf16x8 af, bfr[4];
      {
        int rr = wm + row;
        af = *(const bf16x8*)(As + rr * 64 + (((quad + ks * 4) ^ (rr & 7)) << 3));
      }
      for (int j = 0; j < 4; ++j) {
        int rr = wn + j * 16 + row;
        bfr[j] = *(const bf16x8*)(Bs[cur] + rr * 64 + (((quad + ks * 4) ^ (rr & 7)) << 3));
      }
      for (int j = 0; j < 4; ++j)
        acc[j] = __builtin_amdgcn_mfma_f32_16x16x32_bf16(af, bfr[j], acc[j], 0, 0, 0);
    }
    SFENCE();
    SBAR();
  }

  for (int j = 0; j < 4; ++j)
    for (int r = 0; r < 4; ++r) {
      int gm = m0 + wm + quad * 4 + r;
      int gn = n0 + wn + j * 16 + row;
      Cout[(size_t)gm * DMODEL + gn] = acc[j][r];
    }
}

// ---------------------------------------------------------------------------
extern "C" void kernel_launch(void* const* d_in, const int* in_sizes, int n_in,
                              void* d_out, int out_size, void* d_ws, size_t ws_size,
                              hipStream_t stream)
{
  const float* query = (const float*)d_in[0];
  const float* key_  = (const float*)d_in[1];
  const float* value = (const float*)d_in[2];
  const float* mask  = (const float*)d_in[3];
  const float* Wq = (const float*)d_in[4];
  const float* Wk = (const float*)d_in[5];
  const float* Wv = (const float*)d_in[6];
  const float* Wo = (const float*)d_in[7];

  char* ws = (char*)d_ws;
  const size_t MB = (size_t)1 << 20;
  bf16* qh    = (bf16*)(ws + 0 * MB);    // 8MB [B,NH,S,DKV]
  bf16* kh    = (bf16*)(ws + 8 * MB);    // 8MB [B,NH,S,DKV]
  bf16* vperm = (bf16*)(ws + 16 * MB);   // 8MB PV-permuted V
  bf16* wot   = (bf16*)(ws + 24 * MB);   // 2MB (live until out-GEMM)
  bf16* Opart = (bf16*)(ws + 26 * MB);   // 16MB bf16 partials (26..42)
  bf16* wqt   = (bf16*)(ws + 26 * MB);   // 2MB each, dead after QKV GEMM
  bf16* wkt   = (bf16*)(ws + 28 * MB);   //   (overlaid by Opart afterwards)
  bf16* wvt   = (bf16*)(ws + 30 * MB);
  float* Lpart = (float*)(ws + 58 * MB); // 512KB row-sum partials

  transpose_w<<<dim3(32, 32, 4), dim3(32, 8), 0, stream>>>(Wq, Wk, Wv, Wo, wqt, wkt, wvt, wot);
  gemm_qkv<<<dim3(32, 8, 3), 256, 0, stream>>>(query, key_, value, wqt, wkt, wvt,
                                               qh, kh, vperm);
  attn_kernel<<<dim3(32, 16, 2), 256, 0, stream>>>(qh, kh, vperm, mask, Opart, Lpart);
  gemm_out<<<dim3(128, 8), 256, 0, stream>>>(Opart, Lpart, wot, (float*)d_out);
}